// Round 21
// baseline (3964.600 us; speedup 1.0000x reference)
//
#include <hip/hip_runtime.h>
#include <math.h>

// ---------------- problem constants ----------------
#define B_  16
#define S_  512
#define D_  1024
#define H_  16
#define DH_ 64
#define L_  8
#define FF_ 4096
#define M_  (B_*S_)   // 8192 tokens

typedef __attribute__((ext_vector_type(4))) float  f32x4;
typedef __attribute__((ext_vector_type(8))) short  s8v;
typedef __attribute__((ext_vector_type(4))) short  s4v;
typedef __attribute__((ext_vector_type(8))) __bf16 bf8v;

// f32 -> bf16 bits, round-to-nearest-even
__device__ __forceinline__ short f2bf(float f) {
  union { float f; unsigned u; } x; x.f = f;
  unsigned r = x.u + 0x7fffu + ((x.u >> 16) & 1u);
  return (short)(r >> 16);
}

__device__ __forceinline__ f32x4 mfma16(s8v a, s8v b, f32x4 c) {
  return __builtin_amdgcn_mfma_f32_16x16x32_bf16(
      __builtin_bit_cast(bf8v, a), __builtin_bit_cast(bf8v, b), c, 0, 0, 0);
}

// async global->LDS, 16B per lane; LDS base wave-uniform, lane*16 implicit
__device__ __forceinline__ void gl_lds16(const void* g, void* lds) {
  __builtin_amdgcn_global_load_lds(
      (const __attribute__((address_space(1))) unsigned int*)g,
      (__attribute__((address_space(3))) unsigned int*)lds, 16, 0, 0);
}

// tanh-form GELU (max abs err ~3e-4 vs exact erf; negligible after W2 + bf16)
__device__ __forceinline__ float gelu_f(float v) {
  const float t  = 0.7978845608f * (v + 0.044715f * v * v * v);
  const float e  = __expf(-2.0f * fabsf(t));
  const float th = copysignf((1.f - e) / (1.f + e), t);
  return 0.5f * v * (1.0f + th);
}

// ---------------- weight transpose + f32->bf16 ----------------
__global__ __launch_bounds__(256) void tcvt(const float* __restrict__ src,
                                            short* __restrict__ dst, int R, int C,
                                            size_t dls) {
  __shared__ float tile[32][33];
  src += (size_t)blockIdx.z * R * C;
  dst += (size_t)blockIdx.z * dls;
  const int c0 = blockIdx.x * 32, r0 = blockIdx.y * 32;
  const int tx = threadIdx.x & 31, ty = threadIdx.x >> 5;
#pragma unroll
  for (int i = 0; i < 32; i += 8)
    tile[ty + i][tx] = src[(size_t)(r0 + ty + i) * C + (c0 + tx)];
  __syncthreads();
#pragma unroll
  for (int i = 0; i < 32; i += 8)
    dst[(size_t)(c0 + ty + i) * R + (r0 + tx)] = f2bf(tile[tx][ty + i]);
}

// ---------------- embeddings + LN -> f32 residual (lives in d_out) ----------------
__global__ __launch_bounds__(256) void embed_ln(
    const int* __restrict__ ids, const int* __restrict__ tts,
    const float* __restrict__ tok, const float* __restrict__ pos,
    const float* __restrict__ typ, const float* __restrict__ g,
    const float* __restrict__ bta, float* __restrict__ h) {
  const int row = blockIdx.x;
  const int s = row & (S_ - 1);
  const int id = ids[row], tt = tts[row];
  const int t = threadIdx.x;
  const float4 a = ((const float4*)(tok + (size_t)id * D_))[t];
  const float4 p = ((const float4*)(pos + (size_t)s  * D_))[t];
  const float4 y = ((const float4*)(typ + (size_t)tt * D_))[t];
  float x0 = a.x + p.x + y.x, x1 = a.y + p.y + y.y;
  float x2 = a.z + p.z + y.z, x3 = a.w + p.w + y.w;
  float sum = x0 + x1 + x2 + x3;
  float sq  = x0*x0 + x1*x1 + x2*x2 + x3*x3;
  __shared__ float red[8];
#pragma unroll
  for (int d = 1; d < 64; d <<= 1) { sum += __shfl_xor(sum, d); sq += __shfl_xor(sq, d); }
  if ((t & 63) == 0) { red[t >> 6] = sum; red[(t >> 6) + 4] = sq; }
  __syncthreads();
  sum = red[0] + red[1] + red[2] + red[3];
  sq  = red[4] + red[5] + red[6] + red[7];
  const float mean = sum * (1.f / D_);
  const float var  = sq * (1.f / D_) - mean * mean;
  const float rstd = rsqrtf(fmaxf(var, 0.f) + 1e-12f);
  const float4 gg = ((const float4*)g)[t];
  const float4 bb = ((const float4*)bta)[t];
  float4 o;
  o.x = (x0 - mean) * rstd * gg.x + bb.x;
  o.y = (x1 - mean) * rstd * gg.y + bb.y;
  o.z = (x2 - mean) * rstd * gg.z + bb.z;
  o.w = (x3 - mean) * rstd * gg.w + bb.w;
  ((float4*)(h + (size_t)row * D_))[t] = o;
}

// ---------------- LN(h) -> bf16 activations ----------------
__global__ __launch_bounds__(256) void ln_bf16(
    const float* __restrict__ h, const float* __restrict__ g,
    const float* __restrict__ bta, short* __restrict__ out) {
  const int row = blockIdx.x;
  const int t = threadIdx.x;
  const float4 x = ((const float4*)(h + (size_t)row * D_))[t];
  float sum = x.x + x.y + x.z + x.w;
  float sq  = x.x*x.x + x.y*x.y + x.z*x.z + x.w*x.w;
  __shared__ float red[8];
#pragma unroll
  for (int d = 1; d < 64; d <<= 1) { sum += __shfl_xor(sum, d); sq += __shfl_xor(sq, d); }
  if ((t & 63) == 0) { red[t >> 6] = sum; red[(t >> 6) + 4] = sq; }
  __syncthreads();
  sum = red[0] + red[1] + red[2] + red[3];
  sq  = red[4] + red[5] + red[6] + red[7];
  const float mean = sum * (1.f / D_);
  const float var  = sq * (1.f / D_) - mean * mean;
  const float rstd = rsqrtf(fmaxf(var, 0.f) + 1e-12f);
  const float4 gg = ((const float4*)g)[t];
  const float4 bb = ((const float4*)bta)[t];
  s4v o;
  o[0] = f2bf((x.x - mean) * rstd * gg.x + bb.x);
  o[1] = f2bf((x.y - mean) * rstd * gg.y + bb.y);
  o[2] = f2bf((x.z - mean) * rstd * gg.z + bb.z);
  o[3] = f2bf((x.w - mean) * rstd * gg.w + bb.w);
  *(s4v*)&out[(size_t)row * D_ + t * 4] = o;
}

// ---------------- fused split-K reduce + residual + LN -> bf16 ----------------
__global__ __launch_bounds__(256) void ln_red(
    float* __restrict__ h, const float* __restrict__ p0,
    const float* __restrict__ p1, const float* __restrict__ badd,
    const float* __restrict__ g, const float* __restrict__ bta,
    short* __restrict__ out) {
  const int row = blockIdx.x;
  const int t = threadIdx.x;
  const size_t off = (size_t)row * D_;
  float4 x = ((const float4*)(h + off))[t];
  const float4 a = ((const float4*)(p0 + off))[t];
  const float4 b = ((const float4*)(p1 + off))[t];
  const float4 c = ((const float4*)badd)[t];
  x.x += a.x + b.x + c.x; x.y += a.y + b.y + c.y;
  x.z += a.z + b.z + c.z; x.w += a.w + b.w + c.w;
  ((float4*)(h + off))[t] = x;
  float sum = x.x + x.y + x.z + x.w;
  float sq  = x.x*x.x + x.y*x.y + x.z*x.z + x.w*x.w;
  __shared__ float red[8];
#pragma unroll
  for (int d = 1; d < 64; d <<= 1) { sum += __shfl_xor(sum, d); sq += __shfl_xor(sq, d); }
  if ((t & 63) == 0) { red[t >> 6] = sum; red[(t >> 6) + 4] = sq; }
  __syncthreads();
  sum = red[0] + red[1] + red[2] + red[3];
  sq  = red[4] + red[5] + red[6] + red[7];
  const float mean = sum * (1.f / D_);
  const float var  = sq * (1.f / D_) - mean * mean;
  const float rstd = rsqrtf(fmaxf(var, 0.f) + 1e-12f);
  const float4 gg = ((const float4*)g)[t];
  const float4 bb = ((const float4*)bta)[t];
  s4v o;
  o[0] = f2bf((x.x - mean) * rstd * gg.x + bb.x);
  o[1] = f2bf((x.y - mean) * rstd * gg.y + bb.y);
  o[2] = f2bf((x.z - mean) * rstd * gg.z + bb.z);
  o[3] = f2bf((x.w - mean) * rstd * gg.w + bb.w);
  *(s4v*)&out[off + t * 4] = o;
}

// final h += p0 + p1 + badd
__global__ __launch_bounds__(256) void final_add(
    float* __restrict__ h, const float* __restrict__ p0,
    const float* __restrict__ p1, const float* __restrict__ badd) {
  const int row = blockIdx.x;
  const int t = threadIdx.x;
  const size_t off = (size_t)row * D_;
  float4 x = ((const float4*)(h + off))[t];
  const float4 a = ((const float4*)(p0 + off))[t];
  const float4 b = ((const float4*)(p1 + off))[t];
  const float4 c = ((const float4*)badd)[t];
  x.x += a.x + b.x + c.x; x.y += a.y + b.y + c.y;
  x.z += a.z + b.z + c.z; x.w += a.w + b.w + c.w;
  ((float4*)(h + off))[t] = x;
}

// ================== 256x256 fat-wave GEMM (4 waves x 128x128) ==================
// 256 thr / 4 waves (2Mx2N), wave-tile 128x128 (acc 8x8), BK=64, LDS 128KB.
// Halves LDS-bytes/FLOP vs the 8-wave 128x64 layout (3072 vs 4608 cyc/iter on
// the LDS pipe). r15-proven 8-phase/16-barrier skeleton, store placement
// IDENTICAL, waits scaled (ST_ = 4 gl_lds): VMC 4->8, 6->12. B-frags double-
// buffered bfA/bfB across the 4 MM quadrants per K-tile.
// MODE 1: gelu->bf16   MODE 2: f32 hres += acc
// MODE 4: split-K=2 partials -> hres + slice*M*D
// MODE 6: merged QKV: Q,K swapped-MFMA scatter; V unswapped -> V^T at out+2*M*D.
template<int MODE>
__global__ __launch_bounds__(256, 1) void gemm8(
    const short* __restrict__ A, const short* __restrict__ Bt,
    const float* __restrict__ b0, const float* __restrict__ b1,
    const float* __restrict__ b2, short* __restrict__ out,
    float* __restrict__ hres, int N, int K, int LD, int nby) {
  __shared__ __align__(16) char lds[131072];
  const int tid = threadIdx.x, wid = tid >> 6, lane = tid & 63;
  const int wr = wid >> 1, wc = wid & 1;
  const int l15 = lane & 15, l4 = lane >> 4;

  const int n8 = (int)gridDim.x >> 3;
  const int bid = (int)blockIdx.x;
  const int xcd = bid & 7, tt_ = bid >> 3;
  const int nbv = (MODE == 4) ? nby * 2 : nby;
  const int cpx = n8 / nbv;
  const int bx = xcd * cpx + tt_ / nbv;
  const int bv = tt_ % nbv;
  const int by = (MODE == 4) ? (bv & 3) : bv;
  const int slice = (MODE == 4) ? (bv >> 2) : 0;
  const int which = (MODE == 6) ? (by >> 2) : 0;   // block-uniform

  const short* __restrict__ Ab = A + (size_t)bx * 256 * LD + (size_t)slice * K;
  const short* __restrict__ Bb = Bt + (size_t)by * 256 * LD + (size_t)slice * K;

  const int str0 = tid >> 3;                       // 0..31
  const int stc  = (((tid & 7) ^ (str0 & 7)) * 8); // shorts (row&7 invariant mod 32)
  const int r7  = l15 & 7;
  const int kx0 = ((l4) ^ r7) * 16;
  const int kx1 = ((4 + l4) ^ r7) * 16;
  const int arow = (wr * 128 + l15) * 128;
  const int brow = (wc * 128 + l15) * 128;

  f32x4 acc[8][8];
#pragma unroll
  for (int m = 0; m < 8; ++m)
#pragma unroll
    for (int n = 0; n < 8; ++n) acc[m][n] = f32x4{0.f, 0.f, 0.f, 0.f};
  s8v af[8][2], bfA[4][2], bfB[4][2];

  const int nt = K >> 6, it = nt >> 1;

#define BAR_ __builtin_amdgcn_s_barrier()
#define LGKM0_ asm volatile("s_waitcnt lgkmcnt(0)" ::: "memory")
#define VMC_(n) asm volatile("s_waitcnt vmcnt(" #n ")" ::: "memory")
// stages one 128-row x 64-col half (16KB): 4 gl_lds16/thread, rows str0+j*32
#define ST_(isB, slot, hh, kt) do { \
    const short* _g = ((isB) ? Bb : Ab) + (size_t)((hh) * 128 + str0) * LD + ((kt) << 6) + stc; \
    char* _d = lds + ((isB) ? 65536 : 0) + (slot) * 32768 + (hh) * 16384 + wid * 1024; \
    gl_lds16(_g, _d); \
    gl_lds16(_g + (size_t)32 * LD, _d + 4096); \
    gl_lds16(_g + (size_t)64 * LD, _d + 8192); \
    gl_lds16(_g + (size_t)96 * LD, _d + 12288); \
  } while (0)
#define RDA4_(slot, g) do { \
    const char* _p = lds + (slot) * 32768 + arow + (g) * 8192; \
    _Pragma("unroll") for (int _i = 0; _i < 4; ++_i) { \
      af[(g)*4+_i][0] = *(const s8v*)(_p + _i * 2048 + kx0); \
      af[(g)*4+_i][1] = *(const s8v*)(_p + _i * 2048 + kx1); } \
  } while (0)
#define RDB4_(slot, g, DST) do { \
    const char* _p = lds + 65536 + (slot) * 32768 + brow + (g) * 8192; \
    _Pragma("unroll") for (int _i = 0; _i < 4; ++_i) { \
      DST[_i][0] = *(const s8v*)(_p + _i * 2048 + kx0); \
      DST[_i][1] = *(const s8v*)(_p + _i * 2048 + kx1); } \
  } while (0)
// one quadrant: A-half aq (4 m-frags) x B-half bq (4 n-frags) = 32 MFMA
#define MM_S(aq, BF, bq) do { \
    __builtin_amdgcn_s_setprio(1); \
    _Pragma("unroll") for (int _mf = 0; _mf < 4; ++_mf) \
    _Pragma("unroll") for (int _nf = 0; _nf < 4; ++_nf) \
    _Pragma("unroll") for (int _ks = 0; _ks < 2; ++_ks) \
      acc[(aq)*4+_mf][(bq)*4+_nf] = \
        mfma16(BF[_nf][_ks], af[(aq)*4+_mf][_ks], acc[(aq)*4+_mf][(bq)*4+_nf]); \
    __builtin_amdgcn_s_setprio(0); \
  } while (0)
#define MM_U(aq, BF, bq) do { \
    __builtin_amdgcn_s_setprio(1); \
    _Pragma("unroll") for (int _mf = 0; _mf < 4; ++_mf) \
    _Pragma("unroll") for (int _nf = 0; _nf < 4; ++_nf) \
    _Pragma("unroll") for (int _ks = 0; _ks < 2; ++_ks) \
      acc[(aq)*4+_mf][(bq)*4+_nf] = \
        mfma16(af[(aq)*4+_mf][_ks], BF[_nf][_ks], acc[(aq)*4+_mf][(bq)*4+_nf]); \
    __builtin_amdgcn_s_setprio(0); \
  } while (0)
// r15 skeleton; reads per phase feed that phase's MM via LGKM0; store placement
// byte-identical to r15 (overwrite always >=1 barrier after last read of region)
#define KLOOP_(MMX) \
  for (int t = 0; t < it; ++t) { \
    const int ka = 2 * t, kb = ka + 1; \
    const bool s2 = (ka + 2) < nt, s3 = (kb + 2) < nt; \
    RDA4_(0, 0); RDA4_(0, 1); RDB4_(0, 0, bfA); \
    ST_(1, 1, 1, kb); \
    BAR_; LGKM0_; MMX(0, bfA, 0); BAR_; \
    RDB4_(0, 1, bfB); \
    BAR_; LGKM0_; MMX(1, bfA, 0); BAR_; \
    if (s2) ST_(1, 0, 0, ka + 2); \
    BAR_; MMX(0, bfB, 1); BAR_; \
    if (s2) { ST_(1, 0, 1, ka + 2); VMC_(8); } else { VMC_(0); } \
    BAR_; MMX(1, bfB, 1); BAR_; \
    RDA4_(1, 0); RDA4_(1, 1); RDB4_(1, 0, bfA); \
    if (s2) ST_(0, 0, 0, ka + 2); \
    BAR_; LGKM0_; MMX(0, bfA, 0); BAR_; \
    RDB4_(1, 1, bfB); \
    if (s2) ST_(0, 0, 1, ka + 2); \
    BAR_; LGKM0_; MMX(1, bfA, 0); BAR_; \
    if (s3) ST_(1, 1, 0, kb + 2); \
    BAR_; MMX(0, bfB, 1); BAR_; \
    if (s3) { ST_(0, 1, 0, kb + 2); ST_(0, 1, 1, kb + 2); VMC_(12); } \
    BAR_; MMX(1, bfB, 1); BAR_; \
  }

  // prologue: tile0 {B0,B1,A0,A1} + tile1 {B0,A0,A1}; vmcnt(12): tile0 landed
  ST_(1,0,0,0); ST_(1,0,1,0); ST_(0,0,0,0); ST_(0,0,1,0);
  ST_(1,1,0,1); ST_(0,1,0,1); ST_(0,1,1,1);
  VMC_(12);
  BAR_;

  if (MODE == 6 && which == 2) { KLOOP_(MM_U); }
  else                         { KLOOP_(MM_S); }

  const int r0 = bx * 256 + wr * 128;
  const int c0 = by * 256 + wc * 128;
  if (MODE == 6 && which == 2) {
    short* __restrict__ vout = out + 2 * (size_t)M_ * D_;   // V^T [B][H][DH][S]
#pragma unroll
    for (int n = 0; n < 8; ++n) {
      const int col = c0 + n * 16 + l15;
      const int colw = col & (D_ - 1);
      const int hd = colw >> 6, dh = colw & 63;
      const float bb = b2[colw];
#pragma unroll
      for (int m = 0; m < 8; ++m) {
        const int row = r0 + m * 16 + l4 * 4;
        const int b = row >> 9, s = row & 511;
        s4v pk;
#pragma unroll
        for (int rr = 0; rr < 4; ++rr) pk[rr] = f2bf(acc[m][n][rr] + bb);
        *(s4v*)&vout[(((size_t)(b * H_ + hd) * DH_) + dh) * S_ + s] = pk;
      }
    }
    return;
  }
  const float* __restrict__ bias = (MODE == 6) ? (which == 0 ? b0 : b1) : b0;
  short* __restrict__ outw = (MODE == 6) ? out + (size_t)which * M_ * D_ : out;
  float* __restrict__ pp =
      (MODE == 4) ? hres + (size_t)slice * ((size_t)M_ * D_) : hres;

  float4 bb4[8];
#pragma unroll
  for (int n = 0; n < 8; ++n) {
    const int colb = c0 + n * 16 + l4 * 4;
    const int colw = colb & (D_ - 1);
    bb4[n] = float4{0.f, 0.f, 0.f, 0.f};
    if (MODE == 6)              bb4[n] = *(const float4*)&bias[colw];
    else if (MODE != 4 && bias) bb4[n] = *(const float4*)&bias[colb];
  }
  // m OUTER, n INNER: one row's chunks issue consecutively -> full-line WC
#pragma unroll
  for (int m = 0; m < 8; ++m) {
    const int row = r0 + m * 16 + l15;
#pragma unroll
    for (int n = 0; n < 8; ++n) {
      const int colb = c0 + n * 16 + l4 * 4;
      const int colw = colb & (D_ - 1);
      float v0 = acc[m][n][0] + bb4[n].x, v1 = acc[m][n][1] + bb4[n].y;
      float v2 = acc[m][n][2] + bb4[n].z, v3 = acc[m][n][3] + bb4[n].w;
      if (MODE == 2) {
        float4* hp = (float4*)&hres[(size_t)row * N + colb];
        float4 hv = *hp;
        hv.x += v0; hv.y += v1; hv.z += v2; hv.w += v3;
        *hp = hv;
      } else if (MODE == 4) {
        float4 pv; pv.x = v0; pv.y = v1; pv.z = v2; pv.w = v3;
        *(float4*)&pp[(size_t)row * N + colb] = pv;
      } else {
        if (MODE == 1) { v0 = gelu_f(v0); v1 = gelu_f(v1); v2 = gelu_f(v2); v3 = gelu_f(v3); }
        s4v pk;
        pk[0] = f2bf(v0); pk[1] = f2bf(v1); pk[2] = f2bf(v2); pk[3] = f2bf(v3);
        if (MODE == 6) {
          const int b = row >> 9, s = row & 511, hd = colw >> 6, dh = colw & 63;
          *(s4v*)&outw[((((size_t)b * H_ + hd) * S_ + s) << 6) + dh] = pk;
        } else {
          *(s4v*)&outw[(size_t)row * N + colb] = pk;
        }
      }
    }
  }
#undef BAR_
#undef LGKM0_
#undef VMC_
#undef ST_
#undef RDA4_
#undef RDB4_
#undef MM_S
#undef MM_U
#undef KLOOP_
}

// ---------------- flash attention (KVBLK=64, V pre-transposed, staged) ----------------
__global__ __launch_bounds__(256, 4) void attn(
    const short* __restrict__ Q, const short* __restrict__ K,
    const short* __restrict__ Vt, short* __restrict__ ctx) {
  __shared__ __align__(16) short Kl[64 * 72];
  __shared__ __align__(16) short Vl[64 * 72];
  __shared__ __align__(16) short Pl[4][32 * 72];

  const int tid = threadIdx.x, wid = tid >> 6, lane = tid & 63;
  const int l15 = lane & 15, l4 = lane >> 4;
  const int bid = (int)blockIdx.x;
  const int xcd = bid & 7, idx = bid >> 3;
  const int bh   = xcd * 32 + (idx >> 2);
  const int qblk = idx & 3;
  const short* Qb = Q  + (size_t)bh * S_ * DH_;
  const short* Kb = K  + (size_t)bh * S_ * DH_;
  const short* Vb = Vt + (size_t)bh * DH_ * S_;

  const int qoff = qblk * 128 + wid * 32;

  s8v qf[2][2];
#pragma unroll
  for (int mf = 0; mf < 2; ++mf)
#pragma unroll
    for (int ks = 0; ks < 2; ++ks)
      qf[mf][ks] = *(const s8v*)&Qb[(size_t)(qoff + mf * 16 + l15) * DH_ + ks * 32 + l4 * 8];

  f32x4 o[2][4];
  float rm[2][4], rs[2][4];
#pragma unroll
  for (int mf = 0; mf < 2; ++mf) {
#pragma unroll
    for (int nf = 0; nf < 4; ++nf) o[mf][nf] = f32x4{0.f, 0.f, 0.f, 0.f};
#pragma unroll
    for (int r = 0; r < 4; ++r) { rm[mf][r] = -1e30f; rs[mf][r] = 0.f; }
  }

  const int srow = tid >> 3;
  const int sch  = (tid & 7) * 8;

  s8v rk[2], rv[2];
#pragma unroll
  for (int r = 0; r < 2; ++r) {
    rk[r] = *(const s8v*)&Kb[(size_t)(srow + r * 32) * DH_ + sch];
    rv[r] = *(const s8v*)&Vb[(size_t)(srow + r * 32) * S_ + sch];
  }

  for (int kt = 0; kt < S_ / 64; ++kt) {
    __syncthreads();
#pragma unroll
    for (int r = 0; r < 2; ++r) {
      *(s8v*)&Kl[(srow + r * 32) * 72 + sch] = rk[r];
      *(s8v*)&Vl[(srow + r * 32) * 72 + sch] = rv[r];
    }
    __syncthreads();
    if (kt + 1 < S_ / 64) {
#pragma unroll
      for (int r = 0; r < 2; ++r) {
        rk[r] = *(const s8v*)&Kb[(size_t)((kt + 1) * 64 + srow + r * 32) * DH_ + sch];
        rv[r] = *(const s8v*)&Vb[(size_t)(srow + r * 32) * S_ + (kt + 1) * 64 + sch];
      }
    }

    f32x4 sc[2][4];
#pragma unroll
    for (int mf = 0; mf < 2; ++mf)
#pragma unroll
      for (int nt = 0; nt < 4; ++nt) sc[mf][nt] = f32x4{0.f, 0.f, 0.f, 0.f};
    __builtin_amdgcn_s_setprio(1);
#pragma unroll
    for (int nt = 0; nt < 4; ++nt)
#pragma unroll
      for (int ks = 0; ks < 2; ++ks) {
        const s8v kf = *(const s8v*)&Kl[(nt * 16 + l15) * 72 + ks * 32 + l4 * 8];
#pragma unroll
        for (int mf = 0; mf < 2; ++mf)
          sc[mf][nt] = mfma16(qf[mf][ks], kf, sc[mf][nt]);
      }
    __builtin_amdgcn_s_setprio(0);

#pragma unroll
    for (int mf = 0; mf < 2; ++mf) {
      float tm[4];
#pragma unroll
      for (int r = 0; r < 4; ++r) {
        sc[mf][0][r] *= 0.125f; sc[mf][1][r] *= 0.125f;
        sc[mf][2][r] *= 0.125f; sc[mf][3][r] *= 0.125f;
        tm[r] = fmaxf(fmaxf(sc[mf][0][r], sc[mf][1][r]),
                      fmaxf(sc[mf][2][r], sc[mf][3][r]));
      }
#pragma unroll
      for (int d = 1; d < 16; d <<= 1)
#pragma unroll
        for (int r = 0; r < 4; ++r) tm[r] = fmaxf(tm[r], __shfl_xor(tm[r], d));
      float ps[4];
#pragma unroll
      for (int r = 0; r < 4; ++r) {
        const float nm = fmaxf(rm[mf][r], tm[r]);
        const float so = __expf(rm[mf][r] - nm);
        rm[mf][r] = nm;
        rs[mf][r] *= so;
#pragma unroll
        for (int nf = 0; nf < 4; ++nf) o[mf][nf][r] *= so;
        float psum = 0.f;
#pragma unroll
        for (int nt = 0; nt < 4; ++nt) {
          const float pv = __expf(sc[mf][nt][r] - nm);
          sc[mf][nt][r] = pv;
          psum += pv;
        }
        ps[r] = psum;
      }
#pragma unroll
      for (int d = 1; d < 16; d <<= 1)
#pragma unroll
        for (int r = 0; r < 4; ++r) ps[r] += __shfl_xor(ps[r], d);
#pragma unroll
      for (int r = 0; r < 4; ++r) rs[mf][r] += ps[r];
#pragma unroll
      for (int nt = 0; nt < 4; ++nt)
#pragma unroll
        for (int r = 0; r < 4; ++r)
          Pl[wid][(mf * 16 + l4 * 4 + r) * 72 + nt * 16 + l15] = f2bf(sc[mf][nt][r]);
    }
    asm volatile("s_waitcnt lgkmcnt(0)" ::: "memory");

    __builtin_amdgcn_s_setprio(1);
#pragma unroll
    for (int ks = 0; ks < 2; ++ks) {
      s8v pf[2], vf[4];
#pragma unroll
      for (int mf = 0; mf < 2; ++mf)
        pf[mf] = *(const s8v*)&Pl[wid][(mf * 16 + l15) * 72 + ks * 32 + l4 * 8];
#pragma unroll
      for (int nf = 0; nf < 4; ++nf)
        vf[nf] = *(const s8v*)&Vl[(nf * 16 + l15) * 72 + ks * 32 + l4 * 8];
#pragma unroll
      for (int mf = 0; mf < 2; ++mf)
#pragma unroll
        for (int nf = 0; nf < 4; ++nf)
          o[mf][nf] = mfma16(pf[mf], vf[nf], o[mf][nf]);
    }
    __builtin_amdgcn_s_setprio(0);
  }

  const int bb = bh >> 4, hh = bh & 15;
#pragma unroll
  for (int mf = 0; mf < 2; ++mf)
#pragma unroll
    for (int r = 0; r < 4; ++r) {
      const int qrow = qoff + mf * 16 + l4 * 4 + r;
      const float inv = 1.0f / rs[mf][r];
      short* dst = ctx + (size_t)(bb * S_ + qrow) * D_ + hh * DH_;
#pragma unroll
      for (int nf = 0; nf < 4; ++nf)
        dst[nf * 16 + l15] = f2bf(o[mf][nf][r] * inv);
    }
}

// ---------------- host ----------------
extern "C" void kernel_launch(void* const* d_in, const int* in_sizes, int n_in,
                              void* d_out, int out_size, void* d_ws, size_t ws_size,
                              hipStream_t stream) {
  const int*   ids = (const int*)d_in[0];
  const int*   tts = (const int*)d_in[1];
  const float* tok = (const float*)d_in[2];
  const float* pos = (const float*)d_in[3];
  const float* typ = (const float*)d_in[4];
  const float* eg  = (const float*)d_in[5];
  const float* eb  = (const float*)d_in[6];
  const float* Wq  = (const float*)d_in[7];  const float* bq = (const float*)d_in[8];
  const float* Wk  = (const float*)d_in[9];  const float* bk = (const float*)d_in[10];
  const float* Wv  = (const float*)d_in[11]; const float* bv = (const float*)d_in[12];
  const float* Wo  = (const float*)d_in[13]; const float* bo = (const float*)d_in[14];
  const float* g1  = (const float*)d_in[15]; const float* be1 = (const float*)d_in[16];
  const float* g2  = (const float*)d_in[17]; const float* be2 = (const float*)d_in[18];
  const float* W1  = (const float*)d_in[19]; const float* b1 = (const float*)d_in[20];
  const float* W2  = (const float*)d_in[21]; const float* b2 = (const float*)d_in[22];

  float* h = (float*)d_out;  // residual lives in d_out (f32 [M][D])

  const size_t szDD  = (size_t)D_ * D_;
  const size_t szDF  = (size_t)D_ * FF_;
  const size_t xb_b  = (size_t)M_ * D_ * 2;
  const size_t big_b = (size_t)M_ * FF_ * 2;
  const size_t pa_b  = (size_t)M_ * D_ * 4;
  const size_t wfull = (szDD * 4 + szDF * 2) * 2 * L_;
  const bool full = ws_size >= wfull + xb_b + big_b + 8192;
  const bool sk   = ws_size >= wfull + xb_b + big_b + 2 * pa_b + 8192;

  char* p = (char*)d_ws;
  auto alloc = [&](size_t bytes) { char* r = p; p += (bytes + 255) & ~(size_t)255; return r; };
  const size_t wl = full ? L_ : 1;
  short* wqkvT = (short*)alloc(szDD * 3 * 2 * wl);
  short* woT   = (short*)alloc(szDD * 2 * wl);
  short* w1T   = (short*)alloc(szDF * 2 * wl);
  short* w2T   = (short*)alloc(szDF * 2 * wl);
  short* xb  = (short*)alloc(xb_b);
  char*  big = alloc(big_b);
  float* pa0 = sk ? (float*)alloc(pa_b) : nullptr;
  float* pa1 = sk ? (float*)alloc(pa_b) : nullptr;
  short* qb  = (short*)big;                 // Q | K | V^T contiguous
  short* vb  = (short*)(big + 2 * xb_b);
  short* cb  = xb;
  short* tb  = (short*)big;

  if (full) {
    tcvt<<<dim3(D_/32,  D_/32,  L_), 256, 0, stream>>>(Wq, wqkvT,          D_,  D_,  3*szDD);
    tcvt<<<dim3(D_/32,  D_/32,  L_), 256, 0, stream>>>(Wk, wqkvT +   szDD, D_,  D_,  3*szDD);
    tcvt<<<dim3(D_/32,  D_/32,  L_), 256, 0, stream>>>(Wv, wqkvT + 2*szDD, D_,  D_,  3*szDD);
    tcvt<<<dim3(D_/32,  D_/32,  L_), 256, 0, stream>>>(Wo, woT, D_,  D_,  szDD);
    tcvt<<<dim3(FF_/32, D_/32,  L_), 256, 0, stream>>>(W1, w1T, D_,  FF_, szDF);
    tcvt<<<dim3(D_/32,  FF_/32, L_), 256, 0, stream>>>(W2, w2T, FF_, D_,  szDF);
  }

  embed_ln<<<M_, 256, 0, stream>>>(ids, tts, tok, pos, typ, eg, eb, h);

  const int nbx = M_ / 256;  // 32
  for (int l = 0; l < L_; ++l) {
    if (!full) {
      tcvt<<<dim3(D_/32,  D_/32,  1), 256, 0, stream>>>(Wq + (size_t)l*szDD, wqkvT,          D_,  D_,  0);
      tcvt<<<dim3(D_/32,  D_/32,  1), 256, 0, stream>>>(Wk + (size_t)l*szDD, wqkvT +   szDD, D_,  D_,  0);
      tcvt<<<dim3(D_/32,  D_/32,  1), 256, 0, stream>>>(Wv + (size_t)l*szDD, wqkvT + 2*szDD, D_,  D_,  0);
      tcvt<<<dim3(D_/32,  D_/32,  1), 256, 0, stream>>>(Wo + (size_t)l*szDD, woT, D_,  D_,  0);
      tcvt<<<dim3(FF_/32, D_/32,  1), 256, 0, stream>>>(W1 + (size_t)l*szDF, w1T, D_,  FF_, 0);
      tcvt<<<dim3(D_/32,  FF_/32, 1), 256, 0, stream>>>(W2 + (size_t)l*szDF, w2T, FF_, D_,  0);
    }
    const size_t o3 = full ? (size_t)l * 3 * szDD : 0;
    const size_t od = full ? (size_t)l * szDD : 0;
    const size_t of = full ? (size_t)l * szDF : 0;

    if (l == 0 || !sk)
      ln_bf16<<<M_, 256, 0, stream>>>(h, g1 + l*D_, be1 + l*D_, xb);
    else
      ln_red<<<M_, 256, 0, stream>>>(h, pa0, pa1, b2 + (l-1)*D_,
                                     g1 + l*D_, be1 + l*D_, xb);

    gemm8<6><<<nbx * (3*D_/256), 256, 0, stream>>>(
        xb, wqkvT + o3, bq + l*D_, bk + l*D_, bv + l*D_, qb, nullptr, 3*D_, D_, D_, 3*D_/256);

    attn<<<(S_/128) * B_ * H_, 256, 0, stream>>>(
        qb, qb + (size_t)M_*D_, vb, cb);

    if (sk) {
      gemm8<4><<<nbx * (D_/256) * 2, 256, 0, stream>>>(
          cb, woT + od, nullptr, nullptr, nullptr, nullptr, pa0, D_, D_/2, D_, D_/256);
      ln_red<<<M_, 256, 0, stream>>>(h, pa0, pa1, bo + l*D_,
                                     g2 + l*D_, be2 + l*D_, xb);
    } else {
      gemm8<2><<<nbx * (D_/256), 256, 0, stream>>>(
          cb, woT + od, bo + l*D_, nullptr, nullptr, nullptr, h, D_, D_, D_, D_/256);
      ln_bf16<<<M_, 256, 0, stream>>>(h, g2 + l*D_, be2 + l*D_, xb);
    }

    gemm8<1><<<nbx * (FF_/256), 256, 0, stream>>>(
        xb, w1T + of, b1 + l*FF_, nullptr, nullptr, tb, nullptr, FF_, D_, D_, FF_/256);

    if (sk) {
      gemm8<4><<<nbx * (D_/256) * 2, 256, 0, stream>>>(
          tb, w2T + of, nullptr, nullptr, nullptr, nullptr, pa0, D_, FF_/2, FF_, D_/256);
    } else {
      gemm8<2><<<nbx * (D_/256), 256, 0, stream>>>(
          tb, w2T + of, b2 + l*D_, nullptr, nullptr, nullptr, h, D_, FF_, FF_, D_/256);
    }
  }
  if (sk)
    final_add<<<M_, 256, 0, stream>>>(h, pa0, pa1, b2 + (L_-1)*D_);
}

// Round 22
// 3002.204 us; speedup vs baseline: 1.3206x; 1.3206x over previous
//
#include <hip/hip_runtime.h>
#include <math.h>

// ---------------- problem constants ----------------
#define B_  16
#define S_  512
#define D_  1024
#define H_  16
#define DH_ 64
#define L_  8
#define FF_ 4096
#define M_  (B_*S_)   // 8192 tokens

typedef __attribute__((ext_vector_type(4))) float  f32x4;
typedef __attribute__((ext_vector_type(8))) short  s8v;
typedef __attribute__((ext_vector_type(4))) short  s4v;
typedef __attribute__((ext_vector_type(8))) __bf16 bf8v;

// f32 -> bf16 bits, round-to-nearest-even
__device__ __forceinline__ short f2bf(float f) {
  union { float f; unsigned u; } x; x.f = f;
  unsigned r = x.u + 0x7fffu + ((x.u >> 16) & 1u);
  return (short)(r >> 16);
}

__device__ __forceinline__ f32x4 mfma16(s8v a, s8v b, f32x4 c) {
  return __builtin_amdgcn_mfma_f32_16x16x32_bf16(
      __builtin_bit_cast(bf8v, a), __builtin_bit_cast(bf8v, b), c, 0, 0, 0);
}

// async global->LDS, 16B per lane; LDS base wave-uniform, lane*16 implicit
__device__ __forceinline__ void gl_lds16(const void* g, void* lds) {
  __builtin_amdgcn_global_load_lds(
      (const __attribute__((address_space(1))) unsigned int*)g,
      (__attribute__((address_space(3))) unsigned int*)lds, 16, 0, 0);
}

// tanh-form GELU (max abs err ~3e-4 vs exact erf; negligible after W2 + bf16)
__device__ __forceinline__ float gelu_f(float v) {
  const float t  = 0.7978845608f * (v + 0.044715f * v * v * v);
  const float e  = __expf(-2.0f * fabsf(t));
  const float th = copysignf((1.f - e) / (1.f + e), t);
  return 0.5f * v * (1.0f + th);
}

// ---------------- weight transpose + f32->bf16 ----------------
__global__ __launch_bounds__(256) void tcvt(const float* __restrict__ src,
                                            short* __restrict__ dst, int R, int C,
                                            size_t dls) {
  __shared__ float tile[32][33];
  src += (size_t)blockIdx.z * R * C;
  dst += (size_t)blockIdx.z * dls;
  const int c0 = blockIdx.x * 32, r0 = blockIdx.y * 32;
  const int tx = threadIdx.x & 31, ty = threadIdx.x >> 5;
#pragma unroll
  for (int i = 0; i < 32; i += 8)
    tile[ty + i][tx] = src[(size_t)(r0 + ty + i) * C + (c0 + tx)];
  __syncthreads();
#pragma unroll
  for (int i = 0; i < 32; i += 8)
    dst[(size_t)(c0 + ty + i) * R + (r0 + tx)] = f2bf(tile[tx][ty + i]);
}

// ---------------- embeddings + LN -> f32 residual (lives in d_out) ----------------
__global__ __launch_bounds__(256) void embed_ln(
    const int* __restrict__ ids, const int* __restrict__ tts,
    const float* __restrict__ tok, const float* __restrict__ pos,
    const float* __restrict__ typ, const float* __restrict__ g,
    const float* __restrict__ bta, float* __restrict__ h) {
  const int row = blockIdx.x;
  const int s = row & (S_ - 1);
  const int id = ids[row], tt = tts[row];
  const int t = threadIdx.x;
  const float4 a = ((const float4*)(tok + (size_t)id * D_))[t];
  const float4 p = ((const float4*)(pos + (size_t)s  * D_))[t];
  const float4 y = ((const float4*)(typ + (size_t)tt * D_))[t];
  float x0 = a.x + p.x + y.x, x1 = a.y + p.y + y.y;
  float x2 = a.z + p.z + y.z, x3 = a.w + p.w + y.w;
  float sum = x0 + x1 + x2 + x3;
  float sq  = x0*x0 + x1*x1 + x2*x2 + x3*x3;
  __shared__ float red[8];
#pragma unroll
  for (int d = 1; d < 64; d <<= 1) { sum += __shfl_xor(sum, d); sq += __shfl_xor(sq, d); }
  if ((t & 63) == 0) { red[t >> 6] = sum; red[(t >> 6) + 4] = sq; }
  __syncthreads();
  sum = red[0] + red[1] + red[2] + red[3];
  sq  = red[4] + red[5] + red[6] + red[7];
  const float mean = sum * (1.f / D_);
  const float var  = sq * (1.f / D_) - mean * mean;
  const float rstd = rsqrtf(fmaxf(var, 0.f) + 1e-12f);
  const float4 gg = ((const float4*)g)[t];
  const float4 bb = ((const float4*)bta)[t];
  float4 o;
  o.x = (x0 - mean) * rstd * gg.x + bb.x;
  o.y = (x1 - mean) * rstd * gg.y + bb.y;
  o.z = (x2 - mean) * rstd * gg.z + bb.z;
  o.w = (x3 - mean) * rstd * gg.w + bb.w;
  ((float4*)(h + (size_t)row * D_))[t] = o;
}

// ---------------- LN(h) -> bf16 activations ----------------
__global__ __launch_bounds__(256) void ln_bf16(
    const float* __restrict__ h, const float* __restrict__ g,
    const float* __restrict__ bta, short* __restrict__ out) {
  const int row = blockIdx.x;
  const int t = threadIdx.x;
  const float4 x = ((const float4*)(h + (size_t)row * D_))[t];
  float sum = x.x + x.y + x.z + x.w;
  float sq  = x.x*x.x + x.y*x.y + x.z*x.z + x.w*x.w;
  __shared__ float red[8];
#pragma unroll
  for (int d = 1; d < 64; d <<= 1) { sum += __shfl_xor(sum, d); sq += __shfl_xor(sq, d); }
  if ((t & 63) == 0) { red[t >> 6] = sum; red[(t >> 6) + 4] = sq; }
  __syncthreads();
  sum = red[0] + red[1] + red[2] + red[3];
  sq  = red[4] + red[5] + red[6] + red[7];
  const float mean = sum * (1.f / D_);
  const float var  = sq * (1.f / D_) - mean * mean;
  const float rstd = rsqrtf(fmaxf(var, 0.f) + 1e-12f);
  const float4 gg = ((const float4*)g)[t];
  const float4 bb = ((const float4*)bta)[t];
  s4v o;
  o[0] = f2bf((x.x - mean) * rstd * gg.x + bb.x);
  o[1] = f2bf((x.y - mean) * rstd * gg.y + bb.y);
  o[2] = f2bf((x.z - mean) * rstd * gg.z + bb.z);
  o[3] = f2bf((x.w - mean) * rstd * gg.w + bb.w);
  *(s4v*)&out[(size_t)row * D_ + t * 4] = o;
}

// ---------------- fused split-K reduce + residual + LN -> bf16 ----------------
__global__ __launch_bounds__(256) void ln_red(
    float* __restrict__ h, const float* __restrict__ p0,
    const float* __restrict__ p1, const float* __restrict__ badd,
    const float* __restrict__ g, const float* __restrict__ bta,
    short* __restrict__ out) {
  const int row = blockIdx.x;
  const int t = threadIdx.x;
  const size_t off = (size_t)row * D_;
  float4 x = ((const float4*)(h + off))[t];
  const float4 a = ((const float4*)(p0 + off))[t];
  const float4 b = ((const float4*)(p1 + off))[t];
  const float4 c = ((const float4*)badd)[t];
  x.x += a.x + b.x + c.x; x.y += a.y + b.y + c.y;
  x.z += a.z + b.z + c.z; x.w += a.w + b.w + c.w;
  ((float4*)(h + off))[t] = x;
  float sum = x.x + x.y + x.z + x.w;
  float sq  = x.x*x.x + x.y*x.y + x.z*x.z + x.w*x.w;
  __shared__ float red[8];
#pragma unroll
  for (int d = 1; d < 64; d <<= 1) { sum += __shfl_xor(sum, d); sq += __shfl_xor(sq, d); }
  if ((t & 63) == 0) { red[t >> 6] = sum; red[(t >> 6) + 4] = sq; }
  __syncthreads();
  sum = red[0] + red[1] + red[2] + red[3];
  sq  = red[4] + red[5] + red[6] + red[7];
  const float mean = sum * (1.f / D_);
  const float var  = sq * (1.f / D_) - mean * mean;
  const float rstd = rsqrtf(fmaxf(var, 0.f) + 1e-12f);
  const float4 gg = ((const float4*)g)[t];
  const float4 bb = ((const float4*)bta)[t];
  s4v o;
  o[0] = f2bf((x.x - mean) * rstd * gg.x + bb.x);
  o[1] = f2bf((x.y - mean) * rstd * gg.y + bb.y);
  o[2] = f2bf((x.z - mean) * rstd * gg.z + bb.z);
  o[3] = f2bf((x.w - mean) * rstd * gg.w + bb.w);
  *(s4v*)&out[off + t * 4] = o;
}

// final h += p0 + p1 + badd
__global__ __launch_bounds__(256) void final_add(
    float* __restrict__ h, const float* __restrict__ p0,
    const float* __restrict__ p1, const float* __restrict__ badd) {
  const int row = blockIdx.x;
  const int t = threadIdx.x;
  const size_t off = (size_t)row * D_;
  float4 x = ((const float4*)(h + off))[t];
  const float4 a = ((const float4*)(p0 + off))[t];
  const float4 b = ((const float4*)(p1 + off))[t];
  const float4 c = ((const float4*)badd)[t];
  x.x += a.x + b.x + c.x; x.y += a.y + b.y + c.y;
  x.z += a.z + b.z + c.z; x.w += a.w + b.w + c.w;
  ((float4*)(h + off))[t] = x;
}

// ================== 256x256 8-phase GEMM (round-15 proven core) ==================
// 16-barrier loop, distributed stores, VMC(4)/VMC(6); m-outer coalesced epilogue.
// MODE 1: gelu->bf16   MODE 2: f32 hres += acc
// MODE 4: split-K=2 partials -> hres + slice*M*D
// MODE 6: merged QKV: Bt=[3D][D]; which=by>>2 block-uniform; Q,K swapped-MFMA
//         scatter out+which*M*D [B][H][S][DH]; V unswapped -> V^T at out+2*M*D.
template<int MODE>
__global__ __launch_bounds__(512, 1) void gemm8(
    const short* __restrict__ A, const short* __restrict__ Bt,
    const float* __restrict__ b0, const float* __restrict__ b1,
    const float* __restrict__ b2, short* __restrict__ out,
    float* __restrict__ hres, int N, int K, int LD, int nby) {
  __shared__ __align__(16) char lds[131072];
  const int tid = threadIdx.x, wid = tid >> 6, lane = tid & 63;
  const int wr = wid >> 2, wc = wid & 3;
  const int l15 = lane & 15, l4 = lane >> 4;

  const int n8 = (int)gridDim.x >> 3;
  const int bid = (int)blockIdx.x;
  const int xcd = bid & 7, tt_ = bid >> 3;
  const int nbv = (MODE == 4) ? nby * 2 : nby;
  const int cpx = n8 / nbv;
  const int bx = xcd * cpx + tt_ / nbv;
  const int bv = tt_ % nbv;
  const int by = (MODE == 4) ? (bv & 3) : bv;
  const int slice = (MODE == 4) ? (bv >> 2) : 0;
  const int which = (MODE == 6) ? (by >> 2) : 0;   // block-uniform

  const short* __restrict__ Ab = A + (size_t)bx * 256 * LD + (size_t)slice * K;
  const short* __restrict__ Bb = Bt + (size_t)by * 256 * LD + (size_t)slice * K;

  const int str0 = tid >> 3;
  const int stc  = (((tid & 7) ^ (str0 & 7)) * 8);
  const int r7  = l15 & 7;
  const int kx0 = ((l4) ^ r7) * 16;
  const int kx1 = ((4 + l4) ^ r7) * 16;
  const int arow = (wr * 128 + l15) * 128;
  const int brow = (wc * 64 + l15) * 128;

  f32x4 acc[8][4];
#pragma unroll
  for (int m = 0; m < 8; ++m)
#pragma unroll
    for (int n = 0; n < 4; ++n) acc[m][n] = f32x4{0.f, 0.f, 0.f, 0.f};
  s8v af[8][2], bf[4][2];

  const int nt = K >> 6, it = nt >> 1;

#define BAR_ __builtin_amdgcn_s_barrier()
#define LGKM0_ asm volatile("s_waitcnt lgkmcnt(0)" ::: "memory")
#define VMC_(n) asm volatile("s_waitcnt vmcnt(" #n ")" ::: "memory")
#define ST_(isB, slot, hh, kt) do { \
    const short* _g = ((isB) ? Bb : Ab) + (size_t)((hh) * 128 + str0) * LD + ((kt) << 6) + stc; \
    char* _d = lds + ((isB) ? 65536 : 0) + (slot) * 32768 + (hh) * 16384 + wid * 1024; \
    gl_lds16(_g, _d); \
    gl_lds16(_g + (size_t)64 * LD, _d + 8192); \
  } while (0)
#define RDA4_(slot, g) do { \
    const char* _p = lds + (slot) * 32768 + arow + (g) * 8192; \
    _Pragma("unroll") for (int _i = 0; _i < 4; ++_i) { \
      af[(g)*4+_i][0] = *(const s8v*)(_p + _i * 2048 + kx0); \
      af[(g)*4+_i][1] = *(const s8v*)(_p + _i * 2048 + kx1); } \
  } while (0)
#define RDB2_(slot, g) do { \
    const char* _p = lds + 65536 + (slot) * 32768 + brow + (g) * 4096; \
    _Pragma("unroll") for (int _i = 0; _i < 2; ++_i) { \
      bf[(g)*2+_i][0] = *(const s8v*)(_p + _i * 2048 + kx0); \
      bf[(g)*2+_i][1] = *(const s8v*)(_p + _i * 2048 + kx1); } \
  } while (0)
#define MM_S(mq, nq) do { \
    __builtin_amdgcn_s_setprio(1); \
    _Pragma("unroll") for (int _mf = 0; _mf < 4; ++_mf) \
    _Pragma("unroll") for (int _nf = 0; _nf < 2; ++_nf) \
    _Pragma("unroll") for (int _ks = 0; _ks < 2; ++_ks) \
      acc[(mq)*4+_mf][(nq)*2+_nf] = \
        mfma16(bf[(nq)*2+_nf][_ks], af[(mq)*4+_mf][_ks], acc[(mq)*4+_mf][(nq)*2+_nf]); \
    __builtin_amdgcn_s_setprio(0); \
  } while (0)
#define MM_U(mq, nq) do { \
    __builtin_amdgcn_s_setprio(1); \
    _Pragma("unroll") for (int _mf = 0; _mf < 4; ++_mf) \
    _Pragma("unroll") for (int _nf = 0; _nf < 2; ++_nf) \
    _Pragma("unroll") for (int _ks = 0; _ks < 2; ++_ks) \
      acc[(mq)*4+_mf][(nq)*2+_nf] = \
        mfma16(af[(mq)*4+_mf][_ks], bf[(nq)*2+_nf][_ks], acc[(mq)*4+_mf][(nq)*2+_nf]); \
    __builtin_amdgcn_s_setprio(0); \
  } while (0)
#define KLOOP_(MMX) \
  for (int t = 0; t < it; ++t) { \
    const int ka = 2 * t, kb = ka + 1; \
    const bool s2 = (ka + 2) < nt, s3 = (kb + 2) < nt; \
    RDA4_(0, 0); RDB2_(0, 0); \
    ST_(1, 1, 1, kb); \
    BAR_; LGKM0_; MMX(0, 0); BAR_; \
    RDB2_(0, 1); \
    BAR_; LGKM0_; MMX(0, 1); BAR_; \
    RDA4_(0, 1); \
    if (s2) ST_(1, 0, 0, ka + 2); \
    BAR_; LGKM0_; MMX(1, 0); BAR_; \
    if (s2) { ST_(1, 0, 1, ka + 2); VMC_(4); } else { VMC_(0); } \
    BAR_; MMX(1, 1); BAR_; \
    RDA4_(1, 0); RDB2_(1, 0); \
    if (s2) ST_(0, 0, 0, ka + 2); \
    BAR_; LGKM0_; MMX(0, 0); BAR_; \
    RDB2_(1, 1); \
    if (s2) ST_(0, 0, 1, ka + 2); \
    BAR_; LGKM0_; MMX(0, 1); BAR_; \
    RDA4_(1, 1); \
    if (s3) ST_(1, 1, 0, kb + 2); \
    BAR_; LGKM0_; MMX(1, 0); BAR_; \
    if (s3) { ST_(0, 1, 0, kb + 2); ST_(0, 1, 1, kb + 2); VMC_(6); } \
    BAR_; MMX(1, 1); BAR_; \
  }

  // prologue: tile0 {B0,B1,A0,A1} + tile1 {B0,A0,A1}; vmcnt(6): tile0 landed
  ST_(1,0,0,0); ST_(1,0,1,0); ST_(0,0,0,0); ST_(0,0,1,0);
  ST_(1,1,0,1); ST_(0,1,0,1); ST_(0,1,1,1);
  VMC_(6);
  BAR_;

  if (MODE == 6 && which == 2) { KLOOP_(MM_U); }
  else                         { KLOOP_(MM_S); }

  const int r0 = bx * 256 + wr * 128;
  const int c0 = by * 256 + wc * 64;
  if (MODE == 6 && which == 2) {
    short* __restrict__ vout = out + 2 * (size_t)M_ * D_;   // V^T [B][H][DH][S]
#pragma unroll
    for (int n = 0; n < 4; ++n) {
      const int col = c0 + n * 16 + l15;
      const int colw = col & (D_ - 1);
      const int hd = colw >> 6, dh = colw & 63;
      const float bb = b2[colw];
#pragma unroll
      for (int m = 0; m < 8; ++m) {
        const int row = r0 + m * 16 + l4 * 4;
        const int b = row >> 9, s = row & 511;
        s4v pk;
#pragma unroll
        for (int rr = 0; rr < 4; ++rr) pk[rr] = f2bf(acc[m][n][rr] + bb);
        *(s4v*)&vout[(((size_t)(b * H_ + hd) * DH_) + dh) * S_ + s] = pk;
      }
    }
    return;
  }
  const float* __restrict__ bias = (MODE == 6) ? (which == 0 ? b0 : b1) : b0;
  short* __restrict__ outw = (MODE == 6) ? out + (size_t)which * M_ * D_ : out;
  float* __restrict__ pp =
      (MODE == 4) ? hres + (size_t)slice * ((size_t)M_ * D_) : hres;

  float4 bb4[4];
#pragma unroll
  for (int n = 0; n < 4; ++n) {
    const int colb = c0 + n * 16 + l4 * 4;
    const int colw = colb & (D_ - 1);
    bb4[n] = float4{0.f, 0.f, 0.f, 0.f};
    if (MODE == 6)              bb4[n] = *(const float4*)&bias[colw];
    else if (MODE != 4 && bias) bb4[n] = *(const float4*)&bias[colb];
  }
  // m OUTER, n INNER: one row's 4 chunks issue consecutively -> full-line WC
#pragma unroll
  for (int m = 0; m < 8; ++m) {
    const int row = r0 + m * 16 + l15;
#pragma unroll
    for (int n = 0; n < 4; ++n) {
      const int colb = c0 + n * 16 + l4 * 4;
      const int colw = colb & (D_ - 1);
      float v0 = acc[m][n][0] + bb4[n].x, v1 = acc[m][n][1] + bb4[n].y;
      float v2 = acc[m][n][2] + bb4[n].z, v3 = acc[m][n][3] + bb4[n].w;
      if (MODE == 2) {
        float4* hp = (float4*)&hres[(size_t)row * N + colb];
        float4 hv = *hp;
        hv.x += v0; hv.y += v1; hv.z += v2; hv.w += v3;
        *hp = hv;
      } else if (MODE == 4) {
        float4 pv; pv.x = v0; pv.y = v1; pv.z = v2; pv.w = v3;
        *(float4*)&pp[(size_t)row * N + colb] = pv;
      } else {
        if (MODE == 1) { v0 = gelu_f(v0); v1 = gelu_f(v1); v2 = gelu_f(v2); v3 = gelu_f(v3); }
        s4v pk;
        pk[0] = f2bf(v0); pk[1] = f2bf(v1); pk[2] = f2bf(v2); pk[3] = f2bf(v3);
        if (MODE == 6) {
          const int b = row >> 9, s = row & 511, hd = colw >> 6, dh = colw & 63;
          *(s4v*)&outw[((((size_t)b * H_ + hd) * S_ + s) << 6) + dh] = pk;
        } else {
          *(s4v*)&outw[(size_t)row * N + colb] = pk;
        }
      }
    }
  }
#undef BAR_
#undef LGKM0_
#undef VMC_
#undef ST_
#undef RDA4_
#undef RDB2_
#undef MM_S
#undef MM_U
#undef KLOOP_
}

// ---------------- flash attention (KVBLK=64, V pre-transposed, staged) ----------------
// XCD-affinity block map + K/V LDS staging with register prefetch (staging
// provides the prefetch distance that hides L2 latency — r19's de-staged
// variant exposed ~200cy L2 latency per fragment and was 2x slower).
__global__ __launch_bounds__(256, 4) void attn(
    const short* __restrict__ Q, const short* __restrict__ K,
    const short* __restrict__ Vt, short* __restrict__ ctx) {
  __shared__ __align__(16) short Kl[64 * 72];
  __shared__ __align__(16) short Vl[64 * 72];
  __shared__ __align__(16) short Pl[4][32 * 72];

  const int tid = threadIdx.x, wid = tid >> 6, lane = tid & 63;
  const int l15 = lane & 15, l4 = lane >> 4;
  const int bid = (int)blockIdx.x;
  const int xcd = bid & 7, idx = bid >> 3;       // idx 0..127
  const int bh   = xcd * 32 + (idx >> 2);        // 32 bh per XCD
  const int qblk = idx & 3;
  const short* Qb = Q  + (size_t)bh * S_ * DH_;
  const short* Kb = K  + (size_t)bh * S_ * DH_;
  const short* Vb = Vt + (size_t)bh * DH_ * S_;

  const int qoff = qblk * 128 + wid * 32;

  s8v qf[2][2];
#pragma unroll
  for (int mf = 0; mf < 2; ++mf)
#pragma unroll
    for (int ks = 0; ks < 2; ++ks)
      qf[mf][ks] = *(const s8v*)&Qb[(size_t)(qoff + mf * 16 + l15) * DH_ + ks * 32 + l4 * 8];

  f32x4 o[2][4];
  float rm[2][4], rs[2][4];
#pragma unroll
  for (int mf = 0; mf < 2; ++mf) {
#pragma unroll
    for (int nf = 0; nf < 4; ++nf) o[mf][nf] = f32x4{0.f, 0.f, 0.f, 0.f};
#pragma unroll
    for (int r = 0; r < 4; ++r) { rm[mf][r] = -1e30f; rs[mf][r] = 0.f; }
  }

  const int srow = tid >> 3;
  const int sch  = (tid & 7) * 8;

  s8v rk[2], rv[2];
#pragma unroll
  for (int r = 0; r < 2; ++r) {
    rk[r] = *(const s8v*)&Kb[(size_t)(srow + r * 32) * DH_ + sch];
    rv[r] = *(const s8v*)&Vb[(size_t)(srow + r * 32) * S_ + sch];
  }

  for (int kt = 0; kt < S_ / 64; ++kt) {
    __syncthreads();
#pragma unroll
    for (int r = 0; r < 2; ++r) {
      *(s8v*)&Kl[(srow + r * 32) * 72 + sch] = rk[r];
      *(s8v*)&Vl[(srow + r * 32) * 72 + sch] = rv[r];
    }
    __syncthreads();
    if (kt + 1 < S_ / 64) {
#pragma unroll
      for (int r = 0; r < 2; ++r) {
        rk[r] = *(const s8v*)&Kb[(size_t)((kt + 1) * 64 + srow + r * 32) * DH_ + sch];
        rv[r] = *(const s8v*)&Vb[(size_t)(srow + r * 32) * S_ + (kt + 1) * 64 + sch];
      }
    }

    f32x4 sc[2][4];
#pragma unroll
    for (int mf = 0; mf < 2; ++mf)
#pragma unroll
      for (int nt = 0; nt < 4; ++nt) sc[mf][nt] = f32x4{0.f, 0.f, 0.f, 0.f};
    __builtin_amdgcn_s_setprio(1);
#pragma unroll
    for (int nt = 0; nt < 4; ++nt)
#pragma unroll
      for (int ks = 0; ks < 2; ++ks) {
        const s8v kf = *(const s8v*)&Kl[(nt * 16 + l15) * 72 + ks * 32 + l4 * 8];
#pragma unroll
        for (int mf = 0; mf < 2; ++mf)
          sc[mf][nt] = mfma16(qf[mf][ks], kf, sc[mf][nt]);
      }
    __builtin_amdgcn_s_setprio(0);

#pragma unroll
    for (int mf = 0; mf < 2; ++mf) {
      float tm[4];
#pragma unroll
      for (int r = 0; r < 4; ++r) {
        sc[mf][0][r] *= 0.125f; sc[mf][1][r] *= 0.125f;
        sc[mf][2][r] *= 0.125f; sc[mf][3][r] *= 0.125f;
        tm[r] = fmaxf(fmaxf(sc[mf][0][r], sc[mf][1][r]),
                      fmaxf(sc[mf][2][r], sc[mf][3][r]));
      }
#pragma unroll
      for (int d = 1; d < 16; d <<= 1)
#pragma unroll
        for (int r = 0; r < 4; ++r) tm[r] = fmaxf(tm[r], __shfl_xor(tm[r], d));
      float ps[4];
#pragma unroll
      for (int r = 0; r < 4; ++r) {
        const float nm = fmaxf(rm[mf][r], tm[r]);
        const float so = __expf(rm[mf][r] - nm);
        rm[mf][r] = nm;
        rs[mf][r] *= so;
#pragma unroll
        for (int nf = 0; nf < 4; ++nf) o[mf][nf][r] *= so;
        float psum = 0.f;
#pragma unroll
        for (int nt = 0; nt < 4; ++nt) {
          const float pv = __expf(sc[mf][nt][r] - nm);
          sc[mf][nt][r] = pv;
          psum += pv;
        }
        ps[r] = psum;
      }
#pragma unroll
      for (int d = 1; d < 16; d <<= 1)
#pragma unroll
        for (int r = 0; r < 4; ++r) ps[r] += __shfl_xor(ps[r], d);
#pragma unroll
      for (int r = 0; r < 4; ++r) rs[mf][r] += ps[r];
#pragma unroll
      for (int nt = 0; nt < 4; ++nt)
#pragma unroll
        for (int r = 0; r < 4; ++r)
          Pl[wid][(mf * 16 + l4 * 4 + r) * 72 + nt * 16 + l15] = f2bf(sc[mf][nt][r]);
    }
    asm volatile("s_waitcnt lgkmcnt(0)" ::: "memory");

    __builtin_amdgcn_s_setprio(1);
#pragma unroll
    for (int ks = 0; ks < 2; ++ks) {
      s8v pf[2], vf[4];
#pragma unroll
      for (int mf = 0; mf < 2; ++mf)
        pf[mf] = *(const s8v*)&Pl[wid][(mf * 16 + l15) * 72 + ks * 32 + l4 * 8];
#pragma unroll
      for (int nf = 0; nf < 4; ++nf)
        vf[nf] = *(const s8v*)&Vl[(nf * 16 + l15) * 72 + ks * 32 + l4 * 8];
#pragma unroll
      for (int mf = 0; mf < 2; ++mf)
#pragma unroll
        for (int nf = 0; nf < 4; ++nf)
          o[mf][nf] = mfma16(pf[mf], vf[nf], o[mf][nf]);
    }
    __builtin_amdgcn_s_setprio(0);
  }

  const int bb = bh >> 4, hh = bh & 15;
#pragma unroll
  for (int mf = 0; mf < 2; ++mf)
#pragma unroll
    for (int r = 0; r < 4; ++r) {
      const int qrow = qoff + mf * 16 + l4 * 4 + r;
      const float inv = 1.0f / rs[mf][r];
      short* dst = ctx + (size_t)(bb * S_ + qrow) * D_ + hh * DH_;
#pragma unroll
      for (int nf = 0; nf < 4; ++nf)
        dst[nf * 16 + l15] = f2bf(o[mf][nf][r] * inv);
    }
}

// ---------------- host ----------------
extern "C" void kernel_launch(void* const* d_in, const int* in_sizes, int n_in,
                              void* d_out, int out_size, void* d_ws, size_t ws_size,
                              hipStream_t stream) {
  const int*   ids = (const int*)d_in[0];
  const int*   tts = (const int*)d_in[1];
  const float* tok = (const float*)d_in[2];
  const float* pos = (const float*)d_in[3];
  const float* typ = (const float*)d_in[4];
  const float* eg  = (const float*)d_in[5];
  const float* eb  = (const float*)d_in[6];
  const float* Wq  = (const float*)d_in[7];  const float* bq = (const float*)d_in[8];
  const float* Wk  = (const float*)d_in[9];  const float* bk = (const float*)d_in[10];
  const float* Wv  = (const float*)d_in[11]; const float* bv = (const float*)d_in[12];
  const float* Wo  = (const float*)d_in[13]; const float* bo = (const float*)d_in[14];
  const float* g1  = (const float*)d_in[15]; const float* be1 = (const float*)d_in[16];
  const float* g2  = (const float*)d_in[17]; const float* be2 = (const float*)d_in[18];
  const float* W1  = (const float*)d_in[19]; const float* b1 = (const float*)d_in[20];
  const float* W2  = (const float*)d_in[21]; const float* b2 = (const float*)d_in[22];

  float* h = (float*)d_out;  // residual lives in d_out (f32 [M][D])

  const size_t szDD  = (size_t)D_ * D_;
  const size_t szDF  = (size_t)D_ * FF_;
  const size_t xb_b  = (size_t)M_ * D_ * 2;
  const size_t big_b = (size_t)M_ * FF_ * 2;
  const size_t pa_b  = (size_t)M_ * D_ * 4;
  const size_t wfull = (szDD * 4 + szDF * 2) * 2 * L_;
  const bool full = ws_size >= wfull + xb_b + big_b + 8192;
  const bool sk   = ws_size >= wfull + xb_b + big_b + 2 * pa_b + 8192;

  char* p = (char*)d_ws;
  auto alloc = [&](size_t bytes) { char* r = p; p += (bytes + 255) & ~(size_t)255; return r; };
  const size_t wl = full ? L_ : 1;
  short* wqkvT = (short*)alloc(szDD * 3 * 2 * wl);
  short* woT   = (short*)alloc(szDD * 2 * wl);
  short* w1T   = (short*)alloc(szDF * 2 * wl);
  short* w2T   = (short*)alloc(szDF * 2 * wl);
  short* xb  = (short*)alloc(xb_b);
  char*  big = alloc(big_b);
  float* pa0 = sk ? (float*)alloc(pa_b) : nullptr;
  float* pa1 = sk ? (float*)alloc(pa_b) : nullptr;
  short* qb  = (short*)big;                 // Q | K | V^T contiguous
  short* vb  = (short*)(big + 2 * xb_b);
  short* cb  = xb;
  short* tb  = (short*)big;

  if (full) {
    tcvt<<<dim3(D_/32,  D_/32,  L_), 256, 0, stream>>>(Wq, wqkvT,          D_,  D_,  3*szDD);
    tcvt<<<dim3(D_/32,  D_/32,  L_), 256, 0, stream>>>(Wk, wqkvT +   szDD, D_,  D_,  3*szDD);
    tcvt<<<dim3(D_/32,  D_/32,  L_), 256, 0, stream>>>(Wv, wqkvT + 2*szDD, D_,  D_,  3*szDD);
    tcvt<<<dim3(D_/32,  D_/32,  L_), 256, 0, stream>>>(Wo, woT, D_,  D_,  szDD);
    tcvt<<<dim3(FF_/32, D_/32,  L_), 256, 0, stream>>>(W1, w1T, D_,  FF_, szDF);
    tcvt<<<dim3(D_/32,  FF_/32, L_), 256, 0, stream>>>(W2, w2T, FF_, D_,  szDF);
  }

  embed_ln<<<M_, 256, 0, stream>>>(ids, tts, tok, pos, typ, eg, eb, h);

  const int nbx = M_ / 256;  // 32
  for (int l = 0; l < L_; ++l) {
    if (!full) {
      tcvt<<<dim3(D_/32,  D_/32,  1), 256, 0, stream>>>(Wq + (size_t)l*szDD, wqkvT,          D_,  D_,  0);
      tcvt<<<dim3(D_/32,  D_/32,  1), 256, 0, stream>>>(Wk + (size_t)l*szDD, wqkvT +   szDD, D_,  D_,  0);
      tcvt<<<dim3(D_/32,  D_/32,  1), 256, 0, stream>>>(Wv + (size_t)l*szDD, wqkvT + 2*szDD, D_,  D_,  0);
      tcvt<<<dim3(D_/32,  D_/32,  1), 256, 0, stream>>>(Wo + (size_t)l*szDD, woT, D_,  D_,  0);
      tcvt<<<dim3(FF_/32, D_/32,  1), 256, 0, stream>>>(W1 + (size_t)l*szDF, w1T, D_,  FF_, 0);
      tcvt<<<dim3(D_/32,  FF_/32, 1), 256, 0, stream>>>(W2 + (size_t)l*szDF, w2T, FF_, D_,  0);
    }
    const size_t o3 = full ? (size_t)l * 3 * szDD : 0;
    const size_t od = full ? (size_t)l * szDD : 0;
    const size_t of = full ? (size_t)l * szDF : 0;

    if (l == 0 || !sk)
      ln_bf16<<<M_, 256, 0, stream>>>(h, g1 + l*D_, be1 + l*D_, xb);
    else
      ln_red<<<M_, 256, 0, stream>>>(h, pa0, pa1, b2 + (l-1)*D_,
                                     g1 + l*D_, be1 + l*D_, xb);

    gemm8<6><<<nbx * (3*D_/256), 512, 0, stream>>>(
        xb, wqkvT + o3, bq + l*D_, bk + l*D_, bv + l*D_, qb, nullptr, 3*D_, D_, D_, 3*D_/256);

    attn<<<(S_/128) * B_ * H_, 256, 0, stream>>>(
        qb, qb + (size_t)M_*D_, vb, cb);

    if (sk) {
      gemm8<4><<<nbx * (D_/256) * 2, 512, 0, stream>>>(
          cb, woT + od, nullptr, nullptr, nullptr, nullptr, pa0, D_, D_/2, D_, D_/256);
      ln_red<<<M_, 256, 0, stream>>>(h, pa0, pa1, bo + l*D_,
                                     g2 + l*D_, be2 + l*D_, xb);
    } else {
      gemm8<2><<<nbx * (D_/256), 512, 0, stream>>>(
          cb, woT + od, bo + l*D_, nullptr, nullptr, nullptr, h, D_, D_, D_, D_/256);
      ln_bf16<<<M_, 256, 0, stream>>>(h, g2 + l*D_, be2 + l*D_, xb);
    }

    gemm8<1><<<nbx * (FF_/256), 512, 0, stream>>>(
        xb, w1T + of, b1 + l*FF_, nullptr, nullptr, tb, nullptr, FF_, D_, D_, FF_/256);

    if (sk) {
      gemm8<4><<<nbx * (D_/256) * 2, 512, 0, stream>>>(
          tb, w2T + of, nullptr, nullptr, nullptr, nullptr, pa0, D_, FF_/2, FF_, D_/256);
    } else {
      gemm8<2><<<nbx * (D_/256), 512, 0, stream>>>(
          tb, w2T + of, b2 + l*D_, nullptr, nullptr, nullptr, h, D_, FF_, FF_, D_/256);
    }
  }
  if (sk)
    final_add<<<M_, 256, 0, stream>>>(h, pa0, pa1, b2 + (L_-1)*D_);
}